// Round 6
// baseline (213.703 us; speedup 1.0000x reference)
//
#include <hip/hip_runtime.h>
#include <cfloat>
#include <cstdint>

#define AN 100000   // anchors
#define GN 512      // ground truths
#define NC 80       // classes
#define KK 13       // topk

#define CHUNKS 16
#define CH_LEN 6400               // 15*6400 + 4000 = 100000
#define DUMP 16                   // dump slots per (g, chunk): 13 + pad
#define GSLICE 8
#define GPS (GN / GSLICE)         // 64

typedef unsigned long long ull;

// iou^6 only (no score) — same op order as the original metric for bit-identity
__device__ __forceinline__ float iou6_f(float4 g, float ga, float4 p)
{
    float pa = (p.z - p.x) * (p.w - p.y);
    float ltx = fmaxf(g.x, p.x), lty = fmaxf(g.y, p.y);
    float rbx = fminf(g.z, p.z), rby = fminf(g.w, p.w);
    float w = fmaxf(rbx - ltx, 0.0f), h = fmaxf(rby - lty, 0.0f);
    float inter = w * h;
    float uni = ga + pa - inter;
    float iou = inter / (uni + 1e-9f);
    float i2 = iou * iou;
    return i2 * i2 * i2;
}

// order-preserving float->uint map (total order; works for -FLT_MAX sentinel)
__device__ __forceinline__ unsigned f2ord(float f)
{
    unsigned b = __float_as_uint(f);
    return b ^ (unsigned)(((int)b >> 31) | 0x80000000);
}
__device__ __forceinline__ float ord2f(unsigned u)
{
    unsigned b = (u & 0x80000000u) ? (u ^ 0x80000000u) : ~u;
    return __uint_as_float(b);
}

// compare-swap: keep better (value desc, index asc) in (va, ia)
__device__ __forceinline__ void csw(float& va, int& ia, float& vb, int& ib)
{
    bool sw = (va < vb) || (va == vb && ia > ib);
    float tv = sw ? vb : va; int ti = sw ? ib : ia;
    vb = sw ? va : vb; ib = sw ? ia : ib;
    va = tv; ia = ti;
}

// wave-synchronous LDS fence
__device__ __forceinline__ void wsync()
{
    __builtin_amdgcn_sched_barrier(0);
    asm volatile("s_waitcnt lgkmcnt(0)" ::: "memory");
    __builtin_amdgcn_sched_barrier(0);
}

// Exact top-13 of {incumbents (lane r<13 holds rank r) ∪ cand[0..n)}, n ≤ 511.
// Register-only: lane-strided load -> Batcher sort-8 -> incumbent merge ->
// 13 rounds of 64-lane u64 shfl_xor argmax. Returns the 13th value (threshold).
__device__ float flush_x(int lane, int n, const float* cand_v, const int* cand_i,
                         float& inc_v, int& inc_i)
{
    wsync();                               // appended cand visible wave-wide
    float v[8]; int ix[8];
    #pragma unroll
    for (int k = 0; k < 8; ++k) {
        int j = lane + (k << 6);
        bool ok = j < n;
        v[k]  = ok ? cand_v[j] : -FLT_MAX;
        ix[k] = ok ? cand_i[j] : 0x7fffffff;
    }
    csw(v[0],ix[0],v[1],ix[1]); csw(v[2],ix[2],v[3],ix[3]);
    csw(v[4],ix[4],v[5],ix[5]); csw(v[6],ix[6],v[7],ix[7]);
    csw(v[0],ix[0],v[2],ix[2]); csw(v[1],ix[1],v[3],ix[3]);
    csw(v[4],ix[4],v[6],ix[6]); csw(v[5],ix[5],v[7],ix[7]);
    csw(v[1],ix[1],v[2],ix[2]); csw(v[5],ix[5],v[6],ix[6]);
    csw(v[0],ix[0],v[4],ix[4]); csw(v[1],ix[1],v[5],ix[5]);
    csw(v[2],ix[2],v[6],ix[6]); csw(v[3],ix[3],v[7],ix[7]);
    csw(v[2],ix[2],v[4],ix[4]); csw(v[3],ix[3],v[5],ix[5]);
    csw(v[1],ix[1],v[2],ix[2]); csw(v[3],ix[3],v[4],ix[4]);
    csw(v[5],ix[5],v[6],ix[6]);
    bool c[8];
    #pragma unroll
    for (int j = 0; j < 8; ++j)
        c[j] = (v[j] > inc_v) || (v[j] == inc_v && ix[j] < inc_i);
    float h[9]; int hi[9];
    h[0] = c[0] ? v[0] : inc_v;  hi[0] = c[0] ? ix[0] : inc_i;
    #pragma unroll
    for (int j = 1; j < 8; ++j) {
        h[j]  = c[j] ? v[j]  : (c[j-1] ? inc_v : v[j-1]);
        hi[j] = c[j] ? ix[j] : (c[j-1] ? inc_i : ix[j-1]);
    }
    h[8] = c[7] ? inc_v : v[7];  hi[8] = c[7] ? inc_i : ix[7];

    float th = -FLT_MAX;
    #pragma unroll
    for (int r = 0; r < KK; ++r) {
        ull myp = ((ull)f2ord(h[0]) << 32) | (unsigned)(~hi[0]);
        ull p = myp;
        #pragma unroll
        for (int o = 32; o >= 1; o >>= 1) {
            ull q = __shfl_xor(p, o);
            p = p > q ? p : q;
        }
        float wv = ord2f((unsigned)(p >> 32));
        int   wi = (int)~((unsigned)p);
        if (lane == r) { inc_v = wv; inc_i = wi; }
        bool pop = (myp == p);
        #pragma unroll
        for (int j = 0; j < 8; ++j) {
            h[j]  = pop ? h[j+1]  : h[j];
            hi[j] = pop ? hi[j+1] : hi[j];
        }
        h[8]  = pop ? -FLT_MAX   : h[8];
        hi[8] = pop ? 0x7fffffff : hi[8];
        th = wv;
    }
    return th;
}

// Insert into register-resident sorted-13 (fallback kernels only).
__device__ __forceinline__ void insert13(float* v, int* ix, float m, int a)
{
    bool worse = (m < v[KK - 1]) || (m == v[KK - 1] && a > ix[KK - 1]);
    if (worse) return;
    int p = 0;
    #pragma unroll
    for (int j = 0; j < KK; ++j)
        p += ((v[j] > m) || (v[j] == m && ix[j] < a)) ? 1 : 0;
    #pragma unroll
    for (int j = KK - 1; j >= 1; --j) {
        bool sh = (j > p);
        v[j]  = sh ? v[j - 1]  : v[j];
        ix[j] = sh ? ix[j - 1] : ix[j];
    }
    #pragma unroll
    for (int j = 0; j < KK; ++j) if (j == p) { v[j] = m; ix[j] = a; }
}

// ---------------- pd_scores [AN][NC] -> scT [NC][AN] ----------------
__global__ __launch_bounds__(256) void transpose_scores(
    const float* __restrict__ ps, float* __restrict__ scT)
{
    __shared__ float tile[64][NC + 1];
    int a0 = blockIdx.x * 64;
    int tid = threadIdx.x;
    for (int i = tid; i < 64 * NC / 4; i += 256) {
        int fi = i * 4;
        int a = fi / NC, c = fi % NC;
        if (a0 + a < AN) {
            float4 v = *reinterpret_cast<const float4*>(ps + (size_t)(a0 + a) * NC + c);
            tile[a][c] = v.x; tile[a][c + 1] = v.y; tile[a][c + 2] = v.z; tile[a][c + 3] = v.w;
        }
    }
    __syncthreads();
    int j = tid & 63, cg = tid >> 6;
    int a = a0 + j;
    if (a < AN) {
        for (int c = cg; c < NC; c += 4)
            scT[(size_t)c * AN + a] = tile[j][c];
    }
}

// ---------------- argmax pass A1: per (anchor-pair, g-slice) partial ----------------
// Prefilter: scores <= 1.0 so m = sc*iou6 <= iou6; if iou6 <= best the update
// (strict >) cannot fire — skip the scT gather. Exact (best starts at -1, so
// i=0 always evaluates fully; thereafter best >= 0 and skipped lanes get m=0).
__global__ __launch_bounds__(256) void argmax_part(
    const float* __restrict__ pd_bboxes,
    const int*   __restrict__ gt_labels,
    const float* __restrict__ gt_bboxes,
    const float* __restrict__ scT,
    ull* __restrict__ part)
{
    __shared__ float4 gb[GPS];
    __shared__ float  ga[GPS];
    __shared__ int    glb[GPS];
    int slice = blockIdx.x & (GSLICE - 1);
    int ab = (blockIdx.x >> 3) * 512;
    int tid = threadIdx.x;
    int g0 = slice * GPS;
    if (tid < GPS) {
        float4 bb = ((const float4*)gt_bboxes)[g0 + tid];
        gb[tid] = bb;
        ga[tid] = (bb.z - bb.x) * (bb.w - bb.y);
        glb[tid] = gt_labels[g0 + tid];
    }
    __syncthreads();
    int aa = ab + tid, ab2 = ab + 256 + tid;
    bool okA = aa < AN, okB = ab2 < AN;
    int ca = okA ? aa : AN - 1, cb = okB ? ab2 : AN - 1;
    float4 pba = ((const float4*)pd_bboxes)[ca];
    float4 pbb = ((const float4*)pd_bboxes)[cb];
    float bestA = -1.0f, bestB = -1.0f;
    int bgA = 0, bgB = 0;
    for (int i = 0; i < GPS; ++i) {
        float4 gx = gb[i];
        float gax = ga[i];
        int lab = glb[i];
        const float* srow = scT + (size_t)lab * AN;
        float i6a = iou6_f(gx, gax, pba);
        float i6b = iou6_f(gx, gax, pbb);
        float sa = (i6a > bestA) ? srow[ca] : 0.0f;   // masked gather
        float sb = (i6b > bestB) ? srow[cb] : 0.0f;
        float ma = sa * i6a;
        float mb = sb * i6b;
        if (ma > bestA) { bestA = ma; bgA = i; }      // strict > => first-occurrence
        if (mb > bestB) { bestB = mb; bgB = i; }
    }
    if (okA)
        part[(size_t)slice * AN + aa] =
            ((ull)__float_as_uint(bestA) << 32) | (ull)(0xFFFFFFFFu - (unsigned)(g0 + bgA));
    if (okB)
        part[(size_t)slice * AN + ab2] =
            ((ull)__float_as_uint(bestB) << 32) | (ull)(0xFFFFFFFFu - (unsigned)(g0 + bgB));
}

// ---------------- argmax pass A2: combine 8 slices, write outputs ----------------
__global__ __launch_bounds__(256) void argmax_combine(
    const ull* __restrict__ part,
    const int* __restrict__ gt_labels,
    const float* __restrict__ gt_bboxes,
    float* __restrict__ out)
{
    int a = blockIdx.x * 256 + threadIdx.x;
    if (a >= AN) return;
    ull p = part[a];
    #pragma unroll
    for (int s = 1; s < GSLICE; ++s) {
        ull q = part[(size_t)s * AN + a];
        p = p > q ? p : q;
    }
    unsigned g = 0xFFFFFFFFu - (unsigned)(p & 0xFFFFFFFFull);
    float best = __uint_as_float((unsigned)(p >> 32));
    out[a] = (best <= 0.0f) ? (float)NC : (float)gt_labels[g];
    ((float4*)(out + AN))[a] = ((const float4*)gt_bboxes)[g];
    out[(size_t)5 * AN + a] = best;
}

// ---------------- topk pass 1 ----------------
// 4 independent waves/block, each owns one (g, chunk). Unit-stride loads;
// iou6-prefilter gates the score gather (exact: m <= iou6, append needs m > th).
template<bool FULL>
__device__ __forceinline__ void tile256(
    int tb, int aend, int lane, uint64_t lt,
    const float4* __restrict__ pd4, const float* __restrict__ srow,
    float4 b, float gax, float& th, int& cnt,
    float* cand_v, int* cand_i, float& inc_v, int& inc_i)
{
    int a0 = tb + lane, a1 = a0 + 64, a2 = a0 + 128, a3 = a0 + 192;
    int c0 = FULL ? a0 : min(a0, AN - 1);
    int c1 = FULL ? a1 : min(a1, AN - 1);
    int c2 = FULL ? a2 : min(a2, AN - 1);
    int c3 = FULL ? a3 : min(a3, AN - 1);
    float4 B0 = pd4[c0], B1 = pd4[c1], B2 = pd4[c2], B3 = pd4[c3];
    float i60 = iou6_f(b, gax, B0);
    float i61 = iou6_f(b, gax, B1);
    float i62 = iou6_f(b, gax, B2);
    float i63 = iou6_f(b, gax, B3);
    bool h0 = (i60 > th) && (FULL || a0 < aend);
    bool h1 = (i61 > th) && (FULL || a1 < aend);
    bool h2 = (i62 > th) && (FULL || a2 < aend);
    bool h3 = (i63 > th) && (FULL || a3 < aend);
    if (__any(h0 | h1 | h2 | h3)) {
        float s0 = h0 ? srow[c0] : 0.0f;      // masked coalesced loads
        float s1 = h1 ? srow[c1] : 0.0f;
        float s2 = h2 ? srow[c2] : 0.0f;
        float s3 = h3 ? srow[c3] : 0.0f;
        float m0 = s0 * i60, m1 = s1 * i61, m2 = s2 * i62, m3 = s3 * i63;
        h0 = h0 && (m0 > th); h1 = h1 && (m1 > th);
        h2 = h2 && (m2 > th); h3 = h3 && (m3 > th);
        uint64_t B;
        B = __ballot(h0);
        if (h0) { int p = cnt + __popcll(B & lt); cand_v[p] = m0; cand_i[p] = a0; }
        cnt += __popcll(B);
        B = __ballot(h1);
        if (h1) { int p = cnt + __popcll(B & lt); cand_v[p] = m1; cand_i[p] = a1; }
        cnt += __popcll(B);
        B = __ballot(h2);
        if (h2) { int p = cnt + __popcll(B & lt); cand_v[p] = m2; cand_i[p] = a2; }
        cnt += __popcll(B);
        B = __ballot(h3);
        if (h3) { int p = cnt + __popcll(B & lt); cand_v[p] = m3; cand_i[p] = a3; }
        cnt += __popcll(B);
        if (cnt >= 256) {             // cap: 255 + 256 = 511 < 512
            th = flush_x(lane, cnt, cand_v, cand_i, inc_v, inc_i);
            cnt = 0;
        }
    }
}

__global__ __launch_bounds__(256, 4) void topk_pass1(
    const float* __restrict__ pd_bboxes,
    const int*   __restrict__ gt_labels,
    const float* __restrict__ gt_bboxes,
    const float* __restrict__ scT,
    float* __restrict__ out_v, int* __restrict__ out_i)
{
    __shared__ float cvA[4][512];
    __shared__ int   ciA[4][512];
    int w = threadIdx.x >> 6, lane = threadIdx.x & 63;
    float* cand_v = cvA[w]; int* cand_i = ciA[w];
    uint64_t lt = (1ull << lane) - 1ull;
    int gid = blockIdx.x * 4 + w;
    int g = gid & (GN - 1), c = gid >> 9;

    float4 b = ((const float4*)gt_bboxes)[g];
    float gax = (b.z - b.x) * (b.w - b.y);
    int lab = gt_labels[g];
    const float* srow = scT + (size_t)lab * AN;
    const float4* pd4 = (const float4*)pd_bboxes;

    int base = c * CH_LEN;
    int len = min(CH_LEN, AN - base);
    int nfull = len >> 8, rem = len & 255;
    int aend = base + len;

    float th = -FLT_MAX; int cnt = 0;
    float inc_v = -FLT_MAX; int inc_i = 0x7fffffff;   // lane r<13: rank r

    for (int it = 0; it < nfull; ++it)
        tile256<true>(base + (it << 8), aend, lane, lt, pd4, srow,
                      b, gax, th, cnt, cand_v, cand_i, inc_v, inc_i);
    if (rem)
        tile256<false>(base + (nfull << 8), aend, lane, lt, pd4, srow,
                       b, gax, th, cnt, cand_v, cand_i, inc_v, inc_i);

    if (cnt > 0)
        flush_x(lane, cnt, cand_v, cand_i, inc_v, inc_i);

    if (lane < DUMP) {
        size_t o = ((size_t)g * CHUNKS + c) * DUMP + lane;
        out_v[o] = (lane < KK) ? inc_v : -FLT_MAX;
        out_i[o] = (lane < KK) ? inc_i : 0x7fffffff;
    }
}

// ---------------- topk pass 2: zero row + merge 16x16 dumps + scatter ----------------
__global__ __launch_bounds__(256) void topk_finalize(
    const float* __restrict__ in_v, const int* __restrict__ in_i,
    float* __restrict__ mask)
{
    int g = blockIdx.x, tid = threadIdx.x;
    float4* row4 = (float4*)(mask + (size_t)g * AN);
    float4 z = make_float4(0.f, 0.f, 0.f, 0.f);
    for (int j = tid; j < AN / 4; j += 256) row4[j] = z;
    __syncthreads();
    if (tid >= 64) return;
    int lane = tid;
    size_t rb = (size_t)g * (CHUNKS * DUMP);     // 256 entries
    float v0 = in_v[rb + lane],       v1 = in_v[rb + 64 + lane];
    float v2 = in_v[rb + 128 + lane], v3 = in_v[rb + 192 + lane];
    int   i0 = in_i[rb + lane],       i1 = in_i[rb + 64 + lane];
    int   i2 = in_i[rb + 128 + lane], i3 = in_i[rb + 192 + lane];
    csw(v0, i0, v1, i1); csw(v2, i2, v3, i3);
    csw(v0, i0, v2, i2); csw(v1, i1, v3, i3);
    csw(v1, i1, v2, i2);                          // sorted desc v0..v3
    #pragma unroll
    for (int r = 0; r < KK; ++r) {
        ull myp = ((ull)f2ord(v0) << 32) | (unsigned)(~i0);
        ull p = myp;
        #pragma unroll
        for (int o = 32; o >= 1; o >>= 1) {
            ull q = __shfl_xor(p, o);
            p = p > q ? p : q;
        }
        int wi = (int)~((unsigned)p);
        if (lane == r) mask[(size_t)g * AN + wi] = 1.0f;
        bool pop = (myp == p);
        v0 = pop ? v1 : v0;  i0 = pop ? i1 : i0;
        v1 = pop ? v2 : v1;  i1 = pop ? i2 : i1;
        v2 = pop ? v3 : v2;  i2 = pop ? i3 : i2;
        v3 = pop ? -FLT_MAX : v3;  i3 = pop ? 0x7fffffff : i3;
    }
}

// ---------------- fallbacks (small workspace) ----------------
__global__ __launch_bounds__(256) void argmax_kernel(
    const float* __restrict__ pd_scores,
    const float* __restrict__ pd_bboxes,
    const int*   __restrict__ gt_labels,
    const float* __restrict__ gt_bboxes,
    const float* __restrict__ scT, int use_t,
    float* __restrict__ out)
{
    __shared__ float4 gb[GN];
    __shared__ float  ga[GN];
    __shared__ int    gl[GN];
    int tid = threadIdx.x;
    for (int g = tid; g < GN; g += 256) {
        float4 b = reinterpret_cast<const float4*>(gt_bboxes)[g];
        gb[g] = b;
        ga[g] = (b.z - b.x) * (b.w - b.y);
        gl[g] = gt_labels[g];
    }
    __syncthreads();
    int a = blockIdx.x * 256 + tid;
    if (a >= AN) return;
    float4 pb = reinterpret_cast<const float4*>(pd_bboxes)[a];
    float best = -1.0f; int bg = 0;
    for (int g = 0; g < GN; ++g) {
        int lab = gl[g];
        float sc = use_t ? scT[(size_t)lab * AN + a] : pd_scores[(size_t)a * NC + lab];
        float m = sc * iou6_f(gb[g], ga[g], pb);
        if (m > best) { best = m; bg = g; }
    }
    out[a] = (best <= 0.0f) ? (float)NC : (float)gl[bg];
    reinterpret_cast<float4*>(out + AN)[a] = gb[bg];
    out[5 * AN + a] = best;
}

__global__ __launch_bounds__(256) void topk_kernel_fallback(
    const float* __restrict__ pd_scores,
    const float* __restrict__ pd_bboxes,
    const int*   __restrict__ gt_labels,
    const float* __restrict__ gt_bboxes,
    const float* __restrict__ scT, int use_t,
    float* __restrict__ mask)
{
    __shared__ float sv[256 * KK];
    __shared__ int   si[256 * KK];
    int g = blockIdx.x, tid = threadIdx.x;
    float4 b = reinterpret_cast<const float4*>(gt_bboxes)[g];
    float gax = (b.z - b.x) * (b.w - b.y);
    int lab = gt_labels[g];
    float v[KK]; int idx[KK];
    #pragma unroll
    for (int j = 0; j < KK; ++j) { v[j] = -FLT_MAX; idx[j] = 0x7fffffff; }
    for (int a = tid; a < AN; a += 256) {
        float4 pb = reinterpret_cast<const float4*>(pd_bboxes)[a];
        float sc = use_t ? scT[(size_t)lab * AN + a] : pd_scores[(size_t)a * NC + lab];
        float m = sc * iou6_f(b, gax, pb);
        insert13(v, idx, m, a);
    }
    #pragma unroll
    for (int j = 0; j < KK; ++j) { sv[tid * KK + j] = v[j]; si[tid * KK + j] = idx[j]; }
    for (int off = 128; off >= 1; off >>= 1) {
        __syncthreads();
        if (tid < off) {
            int i = 0, jj = 0;
            float ov[KK]; int oi[KK];
            #pragma unroll
            for (int t = 0; t < KK; ++t) {
                float va = sv[tid * KK + i];          int ia = si[tid * KK + i];
                float vb = sv[(tid + off) * KK + jj]; int ib = si[(tid + off) * KK + jj];
                bool ta = (va > vb) || (va == vb && ia < ib);
                ov[t] = ta ? va : vb; oi[t] = ta ? ia : ib;
                i += ta ? 1 : 0; jj += ta ? 0 : 1;
            }
            #pragma unroll
            for (int t = 0; t < KK; ++t) { sv[tid * KK + t] = ov[t]; si[tid * KK + t] = oi[t]; }
        }
    }
    __syncthreads();
    if (tid < KK) mask[(size_t)g * AN + si[tid]] = 1.0f;
}

extern "C" void kernel_launch(void* const* d_in, const int* in_sizes, int n_in,
                              void* d_out, int out_size, void* d_ws, size_t ws_size,
                              hipStream_t stream)
{
    const float* pd_scores = (const float*)d_in[0];
    const float* pd_bboxes = (const float*)d_in[1];
    const int*   gt_labels = (const int*)d_in[2];
    const float* gt_bboxes = (const float*)d_in[3];
    float* out  = (float*)d_out;
    float* mask = out + (size_t)6 * AN;

    const size_t scT_b  = (size_t)NC * AN * sizeof(float);           // 32.0 MB
    const size_t auxn   = (size_t)GN * CHUNKS * DUMP;                // 131072
    const size_t aux_b  = auxn * 8;                                  // 1.05 MB
    const size_t part_b = (size_t)GSLICE * AN * sizeof(ull);         // 6.4 MB

    float* scT   = (float*)d_ws;
    float* aux_v = (float*)((char*)d_ws + scT_b);
    int*   aux_i = (int*)(aux_v + auxn);
    ull*   part  = (ull*)((char*)d_ws + scT_b + aux_b);

    if (ws_size >= scT_b + aux_b + part_b) {
        transpose_scores<<<(AN + 63) / 64, 256, 0, stream>>>(pd_scores, scT);
        topk_pass1<<<GN * CHUNKS / 4, 256, 0, stream>>>(
            pd_bboxes, gt_labels, gt_bboxes, scT, aux_v, aux_i);
        topk_finalize<<<GN, 256, 0, stream>>>(aux_v, aux_i, mask);
        argmax_part<<<((AN + 511) / 512) * GSLICE, 256, 0, stream>>>(
            pd_bboxes, gt_labels, gt_bboxes, scT, part);
        argmax_combine<<<(AN + 255) / 256, 256, 0, stream>>>(
            part, gt_labels, gt_bboxes, out);
    } else if (ws_size >= scT_b + aux_b) {
        transpose_scores<<<(AN + 63) / 64, 256, 0, stream>>>(pd_scores, scT);
        topk_pass1<<<GN * CHUNKS / 4, 256, 0, stream>>>(
            pd_bboxes, gt_labels, gt_bboxes, scT, aux_v, aux_i);
        topk_finalize<<<GN, 256, 0, stream>>>(aux_v, aux_i, mask);
        argmax_kernel<<<(AN + 255) / 256, 256, 0, stream>>>(
            pd_scores, pd_bboxes, gt_labels, gt_bboxes, scT, 1, out);
    } else if (ws_size >= scT_b) {
        hipMemsetAsync(mask, 0, (size_t)GN * AN * sizeof(float), stream);
        transpose_scores<<<(AN + 63) / 64, 256, 0, stream>>>(pd_scores, scT);
        argmax_kernel<<<(AN + 255) / 256, 256, 0, stream>>>(
            pd_scores, pd_bboxes, gt_labels, gt_bboxes, scT, 1, out);
        topk_kernel_fallback<<<GN, 256, 0, stream>>>(
            pd_scores, pd_bboxes, gt_labels, gt_bboxes, scT, 1, mask);
    } else {
        hipMemsetAsync(mask, 0, (size_t)GN * AN * sizeof(float), stream);
        argmax_kernel<<<(AN + 255) / 256, 256, 0, stream>>>(
            pd_scores, pd_bboxes, gt_labels, gt_bboxes, scT, 0, out);
        topk_kernel_fallback<<<GN, 256, 0, stream>>>(
            pd_scores, pd_bboxes, gt_labels, gt_bboxes, scT, 0, mask);
    }
}

// Round 7
// 205.838 us; speedup vs baseline: 1.0382x; 1.0382x over previous
//
#include <hip/hip_runtime.h>
#include <cfloat>
#include <cstdint>

#define AN 100000   // anchors
#define GN 512      // ground truths
#define NC 80       // classes
#define KK 13       // topk

#define CHUNKS 8
#define CH_LEN 12544              // 7*12544 = 87808; last chunk 12192
#define DUMP 16                   // dump slots per (g, chunk): 13 + pad
#define GSLICE 8
#define GPS (GN / GSLICE)         // 64

typedef unsigned long long ull;

// iou^6 only (no score) — same op order as the original metric for bit-identity
__device__ __forceinline__ float iou6_f(float4 g, float ga, float4 p)
{
    float pa = (p.z - p.x) * (p.w - p.y);
    float ltx = fmaxf(g.x, p.x), lty = fmaxf(g.y, p.y);
    float rbx = fminf(g.z, p.z), rby = fminf(g.w, p.w);
    float w = fmaxf(rbx - ltx, 0.0f), h = fmaxf(rby - lty, 0.0f);
    float inter = w * h;
    float uni = ga + pa - inter;
    float iou = inter / (uni + 1e-9f);
    float i2 = iou * iou;
    return i2 * i2 * i2;
}

// order-preserving float->uint map (total order; works for -FLT_MAX sentinel)
__device__ __forceinline__ unsigned f2ord(float f)
{
    unsigned b = __float_as_uint(f);
    return b ^ (unsigned)(((int)b >> 31) | 0x80000000);
}
__device__ __forceinline__ float ord2f(unsigned u)
{
    unsigned b = (u & 0x80000000u) ? (u ^ 0x80000000u) : ~u;
    return __uint_as_float(b);
}

// compare-swap: keep better (value desc, index asc) in (va, ia)
__device__ __forceinline__ void csw(float& va, int& ia, float& vb, int& ib)
{
    bool sw = (va < vb) || (va == vb && ia > ib);
    float tv = sw ? vb : va; int ti = sw ? ib : ia;
    vb = sw ? va : vb; ib = sw ? ia : ib;
    va = tv; ia = ti;
}

// wave-synchronous LDS fence
__device__ __forceinline__ void wsync()
{
    __builtin_amdgcn_sched_barrier(0);
    asm volatile("s_waitcnt lgkmcnt(0)" ::: "memory");
    __builtin_amdgcn_sched_barrier(0);
}

// Exact top-13 of {incumbents (lane r<13 holds rank r) ∪ cand[0..n)}, n ≤ 511.
// Register-only: lane-strided load -> Batcher sort-8 -> incumbent merge ->
// 13 rounds of 64-lane u64 shfl_xor argmax. Returns the 13th value (threshold).
__device__ float flush_x(int lane, int n, const float* cand_v, const int* cand_i,
                         float& inc_v, int& inc_i)
{
    wsync();                               // appended cand visible wave-wide
    float v[8]; int ix[8];
    #pragma unroll
    for (int k = 0; k < 8; ++k) {
        int j = lane + (k << 6);
        bool ok = j < n;
        v[k]  = ok ? cand_v[j] : -FLT_MAX;
        ix[k] = ok ? cand_i[j] : 0x7fffffff;
    }
    csw(v[0],ix[0],v[1],ix[1]); csw(v[2],ix[2],v[3],ix[3]);
    csw(v[4],ix[4],v[5],ix[5]); csw(v[6],ix[6],v[7],ix[7]);
    csw(v[0],ix[0],v[2],ix[2]); csw(v[1],ix[1],v[3],ix[3]);
    csw(v[4],ix[4],v[6],ix[6]); csw(v[5],ix[5],v[7],ix[7]);
    csw(v[1],ix[1],v[2],ix[2]); csw(v[5],ix[5],v[6],ix[6]);
    csw(v[0],ix[0],v[4],ix[4]); csw(v[1],ix[1],v[5],ix[5]);
    csw(v[2],ix[2],v[6],ix[6]); csw(v[3],ix[3],v[7],ix[7]);
    csw(v[2],ix[2],v[4],ix[4]); csw(v[3],ix[3],v[5],ix[5]);
    csw(v[1],ix[1],v[2],ix[2]); csw(v[3],ix[3],v[4],ix[4]);
    csw(v[5],ix[5],v[6],ix[6]);
    bool c[8];
    #pragma unroll
    for (int j = 0; j < 8; ++j)
        c[j] = (v[j] > inc_v) || (v[j] == inc_v && ix[j] < inc_i);
    float h[9]; int hi[9];
    h[0] = c[0] ? v[0] : inc_v;  hi[0] = c[0] ? ix[0] : inc_i;
    #pragma unroll
    for (int j = 1; j < 8; ++j) {
        h[j]  = c[j] ? v[j]  : (c[j-1] ? inc_v : v[j-1]);
        hi[j] = c[j] ? ix[j] : (c[j-1] ? inc_i : ix[j-1]);
    }
    h[8] = c[7] ? inc_v : v[7];  hi[8] = c[7] ? inc_i : ix[7];

    float th = -FLT_MAX;
    #pragma unroll
    for (int r = 0; r < KK; ++r) {
        ull myp = ((ull)f2ord(h[0]) << 32) | (unsigned)(~hi[0]);
        ull p = myp;
        #pragma unroll
        for (int o = 32; o >= 1; o >>= 1) {
            ull q = __shfl_xor(p, o);
            p = p > q ? p : q;
        }
        float wv = ord2f((unsigned)(p >> 32));
        int   wi = (int)~((unsigned)p);
        if (lane == r) { inc_v = wv; inc_i = wi; }
        bool pop = (myp == p);
        #pragma unroll
        for (int j = 0; j < 8; ++j) {
            h[j]  = pop ? h[j+1]  : h[j];
            hi[j] = pop ? hi[j+1] : hi[j];
        }
        h[8]  = pop ? -FLT_MAX   : h[8];
        hi[8] = pop ? 0x7fffffff : hi[8];
        th = wv;
    }
    return th;
}

// Insert into register-resident sorted-13 (fallback kernels only).
__device__ __forceinline__ void insert13(float* v, int* ix, float m, int a)
{
    bool worse = (m < v[KK - 1]) || (m == v[KK - 1] && a > ix[KK - 1]);
    if (worse) return;
    int p = 0;
    #pragma unroll
    for (int j = 0; j < KK; ++j)
        p += ((v[j] > m) || (v[j] == m && ix[j] < a)) ? 1 : 0;
    #pragma unroll
    for (int j = KK - 1; j >= 1; --j) {
        bool sh = (j > p);
        v[j]  = sh ? v[j - 1]  : v[j];
        ix[j] = sh ? ix[j - 1] : ix[j];
    }
    #pragma unroll
    for (int j = 0; j < KK; ++j) if (j == p) { v[j] = m; ix[j] = a; }
}

// ---------------- pd_scores [AN][NC] -> scT [NC][AN] ----------------
__global__ __launch_bounds__(256) void transpose_scores(
    const float* __restrict__ ps, float* __restrict__ scT)
{
    __shared__ float tile[64][NC + 1];
    int a0 = blockIdx.x * 64;
    int tid = threadIdx.x;
    for (int i = tid; i < 64 * NC / 4; i += 256) {
        int fi = i * 4;
        int a = fi / NC, c = fi % NC;
        if (a0 + a < AN) {
            float4 v = *reinterpret_cast<const float4*>(ps + (size_t)(a0 + a) * NC + c);
            tile[a][c] = v.x; tile[a][c + 1] = v.y; tile[a][c + 2] = v.z; tile[a][c + 3] = v.w;
        }
    }
    __syncthreads();
    int j = tid & 63, cg = tid >> 6;
    int a = a0 + j;
    if (a < AN) {
        for (int c = cg; c < NC; c += 4)
            scT[(size_t)c * AN + a] = tile[j][c];
    }
}

// ---------------- argmax pass A1: per (anchor-pair, g-slice) partial ----------------
// Prefilter (predicated, no branch): scores <= 1.0 so m = sc*iou6 <= iou6;
// if iou6 <= best the strict-> update cannot fire — skip the scT gather.
__global__ __launch_bounds__(256) void argmax_part(
    const float* __restrict__ pd_bboxes,
    const int*   __restrict__ gt_labels,
    const float* __restrict__ gt_bboxes,
    const float* __restrict__ scT,
    ull* __restrict__ part)
{
    __shared__ float4 gb[GPS];
    __shared__ float  ga[GPS];
    __shared__ int    glb[GPS];
    int slice = blockIdx.x & (GSLICE - 1);
    int ab = (blockIdx.x >> 3) * 512;
    int tid = threadIdx.x;
    int g0 = slice * GPS;
    if (tid < GPS) {
        float4 bb = ((const float4*)gt_bboxes)[g0 + tid];
        gb[tid] = bb;
        ga[tid] = (bb.z - bb.x) * (bb.w - bb.y);
        glb[tid] = gt_labels[g0 + tid];
    }
    __syncthreads();
    int aa = ab + tid, ab2 = ab + 256 + tid;
    bool okA = aa < AN, okB = ab2 < AN;
    int ca = okA ? aa : AN - 1, cb = okB ? ab2 : AN - 1;
    float4 pba = ((const float4*)pd_bboxes)[ca];
    float4 pbb = ((const float4*)pd_bboxes)[cb];
    float bestA = -1.0f, bestB = -1.0f;
    int bgA = 0, bgB = 0;
    for (int i = 0; i < GPS; ++i) {
        float4 gx = gb[i];
        float gax = ga[i];
        int lab = glb[i];
        const float* srow = scT + (size_t)lab * AN;
        float i6a = iou6_f(gx, gax, pba);
        float i6b = iou6_f(gx, gax, pbb);
        float sa = (i6a > bestA) ? srow[ca] : 0.0f;   // predicated gather
        float sb = (i6b > bestB) ? srow[cb] : 0.0f;
        float ma = sa * i6a;
        float mb = sb * i6b;
        if (ma > bestA) { bestA = ma; bgA = i; }      // strict > => first-occurrence
        if (mb > bestB) { bestB = mb; bgB = i; }
    }
    if (okA)
        part[(size_t)slice * AN + aa] =
            ((ull)__float_as_uint(bestA) << 32) | (ull)(0xFFFFFFFFu - (unsigned)(g0 + bgA));
    if (okB)
        part[(size_t)slice * AN + ab2] =
            ((ull)__float_as_uint(bestB) << 32) | (ull)(0xFFFFFFFFu - (unsigned)(g0 + bgB));
}

// ---------------- argmax pass A2: combine 8 slices, write outputs ----------------
__global__ __launch_bounds__(256) void argmax_combine(
    const ull* __restrict__ part,
    const int* __restrict__ gt_labels,
    const float* __restrict__ gt_bboxes,
    float* __restrict__ out)
{
    int a = blockIdx.x * 256 + threadIdx.x;
    if (a >= AN) return;
    ull p = part[a];
    #pragma unroll
    for (int s = 1; s < GSLICE; ++s) {
        ull q = part[(size_t)s * AN + a];
        p = p > q ? p : q;
    }
    unsigned g = 0xFFFFFFFFu - (unsigned)(p & 0xFFFFFFFFull);
    float best = __uint_as_float((unsigned)(p >> 32));
    out[a] = (best <= 0.0f) ? (float)NC : (float)gt_labels[g];
    ((float4*)(out + AN))[a] = ((const float4*)gt_bboxes)[g];
    out[(size_t)5 * AN + a] = best;
}

// ---------------- topk pass 1 ----------------
// 4 independent waves/block, each owns one (g, chunk). Unit-stride,
// UNCONDITIONAL loads, manually software-pipelined (double reg bank):
// tile i+1's 8 loads are issued before tile i is processed.
__device__ __forceinline__ void loadT(int tb, int lane,
    const float4* __restrict__ pd4, const float* __restrict__ srow,
    float4& B0, float4& B1, float4& B2, float4& B3,
    float& s0, float& s1, float& s2, float& s3)
{
    int a0 = tb + lane;
    int c0 = min(a0,       AN - 1);
    int c1 = min(a0 + 64,  AN - 1);
    int c2 = min(a0 + 128, AN - 1);
    int c3 = min(a0 + 192, AN - 1);
    B0 = pd4[c0]; B1 = pd4[c1]; B2 = pd4[c2]; B3 = pd4[c3];
    s0 = srow[c0]; s1 = srow[c1]; s2 = srow[c2]; s3 = srow[c3];
}

__device__ __forceinline__ void procT(
    int tb, int aend, int lane, uint64_t lt,
    float4 B0, float4 B1, float4 B2, float4 B3,
    float s0, float s1, float s2, float s3,
    float4 b, float gax, float& th, int& cnt,
    float* cand_v, int* cand_i, float& inc_v, int& inc_i)
{
    int a0 = tb + lane, a1 = a0 + 64, a2 = a0 + 128, a3 = a0 + 192;
    float m0 = s0 * iou6_f(b, gax, B0);
    float m1 = s1 * iou6_f(b, gax, B1);
    float m2 = s2 * iou6_f(b, gax, B2);
    float m3 = s3 * iou6_f(b, gax, B3);
    // strict >: an item equal to the current exact 13th always loses the
    // index tie (incumbent indices precede current-tile indices) — exact drop.
    bool h0 = (m0 > th) && (a0 < aend);
    bool h1 = (m1 > th) && (a1 < aend);
    bool h2 = (m2 > th) && (a2 < aend);
    bool h3 = (m3 > th) && (a3 < aend);
    if (__any(h0 | h1 | h2 | h3)) {       // rare after warm-up
        uint64_t B;
        B = __ballot(h0);
        if (h0) { int p = cnt + __popcll(B & lt); cand_v[p] = m0; cand_i[p] = a0; }
        cnt += __popcll(B);
        B = __ballot(h1);
        if (h1) { int p = cnt + __popcll(B & lt); cand_v[p] = m1; cand_i[p] = a1; }
        cnt += __popcll(B);
        B = __ballot(h2);
        if (h2) { int p = cnt + __popcll(B & lt); cand_v[p] = m2; cand_i[p] = a2; }
        cnt += __popcll(B);
        B = __ballot(h3);
        if (h3) { int p = cnt + __popcll(B & lt); cand_v[p] = m3; cand_i[p] = a3; }
        cnt += __popcll(B);
        if (cnt >= 256) {                 // cap: 255 + 256 = 511 < 512
            th = flush_x(lane, cnt, cand_v, cand_i, inc_v, inc_i);
            cnt = 0;
        }
    }
}

__global__ __launch_bounds__(256, 4) void topk_pass1(
    const float* __restrict__ pd_bboxes,
    const int*   __restrict__ gt_labels,
    const float* __restrict__ gt_bboxes,
    const float* __restrict__ scT,
    float* __restrict__ out_v, int* __restrict__ out_i)
{
    __shared__ float cvA[4][512];
    __shared__ int   ciA[4][512];
    int w = threadIdx.x >> 6, lane = threadIdx.x & 63;
    float* cand_v = cvA[w]; int* cand_i = ciA[w];
    uint64_t lt = (1ull << lane) - 1ull;
    int gid = blockIdx.x * 4 + w;
    int g = gid & (GN - 1), c = gid >> 9;

    float4 b = ((const float4*)gt_bboxes)[g];
    float gax = (b.z - b.x) * (b.w - b.y);
    int lab = gt_labels[g];
    const float* srow = scT + (size_t)lab * AN;
    const float4* pd4 = (const float4*)pd_bboxes;

    int base = c * CH_LEN;
    int len = min(CH_LEN, AN - base);
    int aend = base + len;
    int NT = (len + 255) >> 8;

    float th = -FLT_MAX; int cnt = 0;
    float inc_v = -FLT_MAX; int inc_i = 0x7fffffff;   // lane r<13: rank r

    // double-buffered pipeline: bank X / bank Y
    float4 X0, X1, X2, X3, Y0, Y1, Y2, Y3;
    float xs0, xs1, xs2, xs3, ys0, ys1, ys2, ys3;

    loadT(base, lane, pd4, srow, X0, X1, X2, X3, xs0, xs1, xs2, xs3);
    int i = 0, tb = base;
    while (true) {
        if (i + 1 < NT)
            loadT(tb + 256, lane, pd4, srow, Y0, Y1, Y2, Y3, ys0, ys1, ys2, ys3);
        procT(tb, aend, lane, lt, X0, X1, X2, X3, xs0, xs1, xs2, xs3,
              b, gax, th, cnt, cand_v, cand_i, inc_v, inc_i);
        ++i; tb += 256;
        if (i >= NT) break;
        if (i + 1 < NT)
            loadT(tb + 256, lane, pd4, srow, X0, X1, X2, X3, xs0, xs1, xs2, xs3);
        procT(tb, aend, lane, lt, Y0, Y1, Y2, Y3, ys0, ys1, ys2, ys3,
              b, gax, th, cnt, cand_v, cand_i, inc_v, inc_i);
        ++i; tb += 256;
        if (i >= NT) break;
    }

    if (cnt > 0)
        flush_x(lane, cnt, cand_v, cand_i, inc_v, inc_i);

    if (lane < DUMP) {
        size_t o = ((size_t)g * CHUNKS + c) * DUMP + lane;
        out_v[o] = (lane < KK) ? inc_v : -FLT_MAX;
        out_i[o] = (lane < KK) ? inc_i : 0x7fffffff;
    }
}

// ---------------- topk pass 2: zero row + merge 8x16 dumps + scatter ----------------
__global__ __launch_bounds__(256) void topk_finalize(
    const float* __restrict__ in_v, const int* __restrict__ in_i,
    float* __restrict__ mask)
{
    int g = blockIdx.x, tid = threadIdx.x;
    float4* row4 = (float4*)(mask + (size_t)g * AN);
    float4 z = make_float4(0.f, 0.f, 0.f, 0.f);
    for (int j = tid; j < AN / 4; j += 256) row4[j] = z;
    __syncthreads();
    if (tid >= 64) return;
    int lane = tid;
    size_t rb = (size_t)g * (CHUNKS * DUMP);     // 128 entries
    float v0 = in_v[rb + lane], v1 = in_v[rb + 64 + lane];
    int   i0 = in_i[rb + lane], i1 = in_i[rb + 64 + lane];
    csw(v0, i0, v1, i1);
    #pragma unroll
    for (int r = 0; r < KK; ++r) {
        ull myp = ((ull)f2ord(v0) << 32) | (unsigned)(~i0);
        ull p = myp;
        #pragma unroll
        for (int o = 32; o >= 1; o >>= 1) {
            ull q = __shfl_xor(p, o);
            p = p > q ? p : q;
        }
        int wi = (int)~((unsigned)p);
        if (lane == r) mask[(size_t)g * AN + wi] = 1.0f;
        bool pop = (myp == p);
        v0 = pop ? v1 : v0;          i0 = pop ? i1 : i0;
        v1 = pop ? -FLT_MAX : v1;    i1 = pop ? 0x7fffffff : i1;
    }
}

// ---------------- fallbacks (small workspace) ----------------
__global__ __launch_bounds__(256) void argmax_kernel(
    const float* __restrict__ pd_scores,
    const float* __restrict__ pd_bboxes,
    const int*   __restrict__ gt_labels,
    const float* __restrict__ gt_bboxes,
    const float* __restrict__ scT, int use_t,
    float* __restrict__ out)
{
    __shared__ float4 gb[GN];
    __shared__ float  ga[GN];
    __shared__ int    gl[GN];
    int tid = threadIdx.x;
    for (int g = tid; g < GN; g += 256) {
        float4 b = reinterpret_cast<const float4*>(gt_bboxes)[g];
        gb[g] = b;
        ga[g] = (b.z - b.x) * (b.w - b.y);
        gl[g] = gt_labels[g];
    }
    __syncthreads();
    int a = blockIdx.x * 256 + tid;
    if (a >= AN) return;
    float4 pb = reinterpret_cast<const float4*>(pd_bboxes)[a];
    float best = -1.0f; int bg = 0;
    for (int g = 0; g < GN; ++g) {
        int lab = gl[g];
        float sc = use_t ? scT[(size_t)lab * AN + a] : pd_scores[(size_t)a * NC + lab];
        float m = sc * iou6_f(gb[g], ga[g], pb);
        if (m > best) { best = m; bg = g; }
    }
    out[a] = (best <= 0.0f) ? (float)NC : (float)gl[bg];
    reinterpret_cast<float4*>(out + AN)[a] = gb[bg];
    out[5 * AN + a] = best;
}

__global__ __launch_bounds__(256) void topk_kernel_fallback(
    const float* __restrict__ pd_scores,
    const float* __restrict__ pd_bboxes,
    const int*   __restrict__ gt_labels,
    const float* __restrict__ gt_bboxes,
    const float* __restrict__ scT, int use_t,
    float* __restrict__ mask)
{
    __shared__ float sv[256 * KK];
    __shared__ int   si[256 * KK];
    int g = blockIdx.x, tid = threadIdx.x;
    float4 b = reinterpret_cast<const float4*>(gt_bboxes)[g];
    float gax = (b.z - b.x) * (b.w - b.y);
    int lab = gt_labels[g];
    float v[KK]; int idx[KK];
    #pragma unroll
    for (int j = 0; j < KK; ++j) { v[j] = -FLT_MAX; idx[j] = 0x7fffffff; }
    for (int a = tid; a < AN; a += 256) {
        float4 pb = reinterpret_cast<const float4*>(pd_bboxes)[a];
        float sc = use_t ? scT[(size_t)lab * AN + a] : pd_scores[(size_t)a * NC + lab];
        float m = sc * iou6_f(b, gax, pb);
        insert13(v, idx, m, a);
    }
    #pragma unroll
    for (int j = 0; j < KK; ++j) { sv[tid * KK + j] = v[j]; si[tid * KK + j] = idx[j]; }
    for (int off = 128; off >= 1; off >>= 1) {
        __syncthreads();
        if (tid < off) {
            int i = 0, jj = 0;
            float ov[KK]; int oi[KK];
            #pragma unroll
            for (int t = 0; t < KK; ++t) {
                float va = sv[tid * KK + i];          int ia = si[tid * KK + i];
                float vb = sv[(tid + off) * KK + jj]; int ib = si[(tid + off) * KK + jj];
                bool ta = (va > vb) || (va == vb && ia < ib);
                ov[t] = ta ? va : vb; oi[t] = ta ? ia : ib;
                i += ta ? 1 : 0; jj += ta ? 0 : 1;
            }
            #pragma unroll
            for (int t = 0; t < KK; ++t) { sv[tid * KK + t] = ov[t]; si[tid * KK + t] = oi[t]; }
        }
    }
    __syncthreads();
    if (tid < KK) mask[(size_t)g * AN + si[tid]] = 1.0f;
}

extern "C" void kernel_launch(void* const* d_in, const int* in_sizes, int n_in,
                              void* d_out, int out_size, void* d_ws, size_t ws_size,
                              hipStream_t stream)
{
    const float* pd_scores = (const float*)d_in[0];
    const float* pd_bboxes = (const float*)d_in[1];
    const int*   gt_labels = (const int*)d_in[2];
    const float* gt_bboxes = (const float*)d_in[3];
    float* out  = (float*)d_out;
    float* mask = out + (size_t)6 * AN;

    const size_t scT_b  = (size_t)NC * AN * sizeof(float);           // 32.0 MB
    const size_t auxn   = (size_t)GN * CHUNKS * DUMP;                // 65536
    const size_t aux_b  = auxn * 8;                                  // 0.5 MB
    const size_t part_b = (size_t)GSLICE * AN * sizeof(ull);         // 6.4 MB

    float* scT   = (float*)d_ws;
    float* aux_v = (float*)((char*)d_ws + scT_b);
    int*   aux_i = (int*)(aux_v + auxn);
    ull*   part  = (ull*)((char*)d_ws + scT_b + aux_b);

    if (ws_size >= scT_b + aux_b + part_b) {
        transpose_scores<<<(AN + 63) / 64, 256, 0, stream>>>(pd_scores, scT);
        topk_pass1<<<GN * CHUNKS / 4, 256, 0, stream>>>(
            pd_bboxes, gt_labels, gt_bboxes, scT, aux_v, aux_i);
        topk_finalize<<<GN, 256, 0, stream>>>(aux_v, aux_i, mask);
        argmax_part<<<((AN + 511) / 512) * GSLICE, 256, 0, stream>>>(
            pd_bboxes, gt_labels, gt_bboxes, scT, part);
        argmax_combine<<<(AN + 255) / 256, 256, 0, stream>>>(
            part, gt_labels, gt_bboxes, out);
    } else if (ws_size >= scT_b + aux_b) {
        transpose_scores<<<(AN + 63) / 64, 256, 0, stream>>>(pd_scores, scT);
        topk_pass1<<<GN * CHUNKS / 4, 256, 0, stream>>>(
            pd_bboxes, gt_labels, gt_bboxes, scT, aux_v, aux_i);
        topk_finalize<<<GN, 256, 0, stream>>>(aux_v, aux_i, mask);
        argmax_kernel<<<(AN + 255) / 256, 256, 0, stream>>>(
            pd_scores, pd_bboxes, gt_labels, gt_bboxes, scT, 1, out);
    } else if (ws_size >= scT_b) {
        hipMemsetAsync(mask, 0, (size_t)GN * AN * sizeof(float), stream);
        transpose_scores<<<(AN + 63) / 64, 256, 0, stream>>>(pd_scores, scT);
        argmax_kernel<<<(AN + 255) / 256, 256, 0, stream>>>(
            pd_scores, pd_bboxes, gt_labels, gt_bboxes, scT, 1, out);
        topk_kernel_fallback<<<GN, 256, 0, stream>>>(
            pd_scores, pd_bboxes, gt_labels, gt_bboxes, scT, 1, mask);
    } else {
        hipMemsetAsync(mask, 0, (size_t)GN * AN * sizeof(float), stream);
        argmax_kernel<<<(AN + 255) / 256, 256, 0, stream>>>(
            pd_scores, pd_bboxes, gt_labels, gt_bboxes, scT, 0, out);
        topk_kernel_fallback<<<GN, 256, 0, stream>>>(
            pd_scores, pd_bboxes, gt_labels, gt_bboxes, scT, 0, mask);
    }
}

// Round 8
// 179.426 us; speedup vs baseline: 1.1910x; 1.1472x over previous
//
#include <hip/hip_runtime.h>
#include <cfloat>
#include <cstdint>

#define AN 100000   // anchors
#define GN 512      // ground truths
#define NC 80       // classes
#define KK 13       // topk

#define CHUNKS 8
#define CH_LEN 12544              // 7*12544 = 87808; last chunk 12192
#define DUMP 16                   // dump slots per (g, chunk): 13 + pad
#define GSLICE 8
#define GPS (GN / GSLICE)         // 64

typedef unsigned long long ull;

// fast reciprocal: v_rcp_f32 (<=1 ulp). Outputs are bf16-compared (threshold
// 1.6); ulp-level shifts can't flip ties that matter (exact-0 ties unaffected).
__device__ __forceinline__ float rcpf(float x)
{
    float r; asm("v_rcp_f32 %0, %1" : "=v"(r) : "v"(x)); return r;
}

// iou^6 (no score)
__device__ __forceinline__ float iou6r(float4 g, float ga, float4 p)
{
    float pa = (p.z - p.x) * (p.w - p.y);
    float ltx = fmaxf(g.x, p.x), lty = fmaxf(g.y, p.y);
    float rbx = fminf(g.z, p.z), rby = fminf(g.w, p.w);
    float w = fmaxf(rbx - ltx, 0.0f), h = fmaxf(rby - lty, 0.0f);
    float inter = w * h;
    float uni = ga + pa - inter;
    float iou = inter * rcpf(uni + 1e-9f);
    float i2 = iou * iou;
    return i2 * i2 * i2;
}

// order-preserving float->uint map (total order; works for -FLT_MAX sentinel)
__device__ __forceinline__ unsigned f2ord(float f)
{
    unsigned b = __float_as_uint(f);
    return b ^ (unsigned)(((int)b >> 31) | 0x80000000);
}
__device__ __forceinline__ float ord2f(unsigned u)
{
    unsigned b = (u & 0x80000000u) ? (u ^ 0x80000000u) : ~u;
    return __uint_as_float(b);
}

// compare-swap: keep better (value desc, index asc) in (va, ia)
__device__ __forceinline__ void csw(float& va, int& ia, float& vb, int& ib)
{
    bool sw = (va < vb) || (va == vb && ia > ib);
    float tv = sw ? vb : va; int ti = sw ? ib : ia;
    vb = sw ? va : vb; ib = sw ? ia : ib;
    va = tv; ia = ti;
}

// wave-synchronous LDS fence
__device__ __forceinline__ void wsync()
{
    __builtin_amdgcn_sched_barrier(0);
    asm volatile("s_waitcnt lgkmcnt(0)" ::: "memory");
    __builtin_amdgcn_sched_barrier(0);
}

// Exact top-13 of {incumbent metrics (lane r<13 holds rank r) ∪ candidates},
// where cand_v holds iou6 and the metric is recomputed here as sc*iou6
// (bit-identical to the direct evaluation). n <= 511.
__device__ float flush_x(int lane, int n, const float* cand_v, const int* cand_i,
                         const float* __restrict__ srow,
                         float& inc_v, int& inc_i)
{
    wsync();                               // appended cand visible wave-wide
    float v[8]; int ix[8];
    #pragma unroll
    for (int k = 0; k < 8; ++k) {
        int j = lane + (k << 6);
        bool ok = j < n;
        float i6 = ok ? cand_v[j] : 0.0f;
        int   ai = ok ? cand_i[j] : 0;
        float sc = srow[ai];               // gather (rare; flush-only)
        v[k]  = ok ? sc * i6 : -FLT_MAX;
        ix[k] = ok ? ai : 0x7fffffff;
    }
    csw(v[0],ix[0],v[1],ix[1]); csw(v[2],ix[2],v[3],ix[3]);
    csw(v[4],ix[4],v[5],ix[5]); csw(v[6],ix[6],v[7],ix[7]);
    csw(v[0],ix[0],v[2],ix[2]); csw(v[1],ix[1],v[3],ix[3]);
    csw(v[4],ix[4],v[6],ix[6]); csw(v[5],ix[5],v[7],ix[7]);
    csw(v[1],ix[1],v[2],ix[2]); csw(v[5],ix[5],v[6],ix[6]);
    csw(v[0],ix[0],v[4],ix[4]); csw(v[1],ix[1],v[5],ix[5]);
    csw(v[2],ix[2],v[6],ix[6]); csw(v[3],ix[3],v[7],ix[7]);
    csw(v[2],ix[2],v[4],ix[4]); csw(v[3],ix[3],v[5],ix[5]);
    csw(v[1],ix[1],v[2],ix[2]); csw(v[3],ix[3],v[4],ix[4]);
    csw(v[5],ix[5],v[6],ix[6]);
    bool c[8];
    #pragma unroll
    for (int j = 0; j < 8; ++j)
        c[j] = (v[j] > inc_v) || (v[j] == inc_v && ix[j] < inc_i);
    float h[9]; int hi[9];
    h[0] = c[0] ? v[0] : inc_v;  hi[0] = c[0] ? ix[0] : inc_i;
    #pragma unroll
    for (int j = 1; j < 8; ++j) {
        h[j]  = c[j] ? v[j]  : (c[j-1] ? inc_v : v[j-1]);
        hi[j] = c[j] ? ix[j] : (c[j-1] ? inc_i : ix[j-1]);
    }
    h[8] = c[7] ? inc_v : v[7];  hi[8] = c[7] ? inc_i : ix[7];

    float th = -FLT_MAX;
    #pragma unroll
    for (int r = 0; r < KK; ++r) {
        ull myp = ((ull)f2ord(h[0]) << 32) | (unsigned)(~hi[0]);
        ull p = myp;
        #pragma unroll
        for (int o = 32; o >= 1; o >>= 1) {
            ull q = __shfl_xor(p, o);
            p = p > q ? p : q;
        }
        float wv = ord2f((unsigned)(p >> 32));
        int   wi = (int)~((unsigned)p);
        if (lane == r) { inc_v = wv; inc_i = wi; }
        bool pop = (myp == p);
        #pragma unroll
        for (int j = 0; j < 8; ++j) {
            h[j]  = pop ? h[j+1]  : h[j];
            hi[j] = pop ? hi[j+1] : hi[j];
        }
        h[8]  = pop ? -FLT_MAX   : h[8];
        hi[8] = pop ? 0x7fffffff : hi[8];
        th = wv;
    }
    return th;
}

// Insert into register-resident sorted-13 (fallback kernels only).
__device__ __forceinline__ void insert13(float* v, int* ix, float m, int a)
{
    bool worse = (m < v[KK - 1]) || (m == v[KK - 1] && a > ix[KK - 1]);
    if (worse) return;
    int p = 0;
    #pragma unroll
    for (int j = 0; j < KK; ++j)
        p += ((v[j] > m) || (v[j] == m && ix[j] < a)) ? 1 : 0;
    #pragma unroll
    for (int j = KK - 1; j >= 1; --j) {
        bool sh = (j > p);
        v[j]  = sh ? v[j - 1]  : v[j];
        ix[j] = sh ? ix[j - 1] : ix[j];
    }
    #pragma unroll
    for (int j = 0; j < KK; ++j) if (j == p) { v[j] = m; ix[j] = a; }
}

// ---------------- pd_scores [AN][NC] -> scT [NC][AN] ----------------
__global__ __launch_bounds__(256) void transpose_scores(
    const float* __restrict__ ps, float* __restrict__ scT)
{
    __shared__ float tile[64][NC + 1];
    int a0 = blockIdx.x * 64;
    int tid = threadIdx.x;
    for (int i = tid; i < 64 * NC / 4; i += 256) {
        int fi = i * 4;
        int a = fi / NC, c = fi % NC;
        if (a0 + a < AN) {
            float4 v = *reinterpret_cast<const float4*>(ps + (size_t)(a0 + a) * NC + c);
            tile[a][c] = v.x; tile[a][c + 1] = v.y; tile[a][c + 2] = v.z; tile[a][c + 3] = v.w;
        }
    }
    __syncthreads();
    int j = tid & 63, cg = tid >> 6;
    int a = a0 + j;
    if (a < AN) {
        for (int c = cg; c < NC; c += 4)
            scT[(size_t)c * AN + a] = tile[j][c];
    }
}

// ---------------- argmax pass A1 ----------------
// Prefilter (predicated): scores <= 1.0 so m = sc*iou6 <= iou6; if
// iou6 <= best the strict-> update cannot fire — skip the scT gather.
__global__ __launch_bounds__(256) void argmax_part(
    const float* __restrict__ pd_bboxes,
    const int*   __restrict__ gt_labels,
    const float* __restrict__ gt_bboxes,
    const float* __restrict__ scT,
    ull* __restrict__ part)
{
    __shared__ float4 gb[GPS];
    __shared__ float  ga[GPS];
    __shared__ int    glb[GPS];
    int slice = blockIdx.x & (GSLICE - 1);
    int ab = (blockIdx.x >> 3) * 512;
    int tid = threadIdx.x;
    int g0 = slice * GPS;
    if (tid < GPS) {
        float4 bb = ((const float4*)gt_bboxes)[g0 + tid];
        gb[tid] = bb;
        ga[tid] = (bb.z - bb.x) * (bb.w - bb.y);
        glb[tid] = gt_labels[g0 + tid];
    }
    __syncthreads();
    int aa = ab + tid, ab2 = ab + 256 + tid;
    bool okA = aa < AN, okB = ab2 < AN;
    int ca = okA ? aa : AN - 1, cb = okB ? ab2 : AN - 1;
    float4 pba = ((const float4*)pd_bboxes)[ca];
    float4 pbb = ((const float4*)pd_bboxes)[cb];
    float bestA = -1.0f, bestB = -1.0f;
    int bgA = 0, bgB = 0;
    for (int i = 0; i < GPS; ++i) {
        float4 gx = gb[i];
        float gax = ga[i];
        int lab = glb[i];
        const float* srow = scT + (size_t)lab * AN;
        float i6a = iou6r(gx, gax, pba);
        float i6b = iou6r(gx, gax, pbb);
        float sa = (i6a > bestA) ? srow[ca] : 0.0f;   // predicated gather
        float sb = (i6b > bestB) ? srow[cb] : 0.0f;
        float ma = sa * i6a;
        float mb = sb * i6b;
        if (ma > bestA) { bestA = ma; bgA = i; }      // strict > => first-occurrence
        if (mb > bestB) { bestB = mb; bgB = i; }
    }
    if (okA)
        part[(size_t)slice * AN + aa] =
            ((ull)__float_as_uint(bestA) << 32) | (ull)(0xFFFFFFFFu - (unsigned)(g0 + bgA));
    if (okB)
        part[(size_t)slice * AN + ab2] =
            ((ull)__float_as_uint(bestB) << 32) | (ull)(0xFFFFFFFFu - (unsigned)(g0 + bgB));
}

// ---------------- argmax pass A2 ----------------
__global__ __launch_bounds__(256) void argmax_combine(
    const ull* __restrict__ part,
    const int* __restrict__ gt_labels,
    const float* __restrict__ gt_bboxes,
    float* __restrict__ out)
{
    int a = blockIdx.x * 256 + threadIdx.x;
    if (a >= AN) return;
    ull p = part[a];
    #pragma unroll
    for (int s = 1; s < GSLICE; ++s) {
        ull q = part[(size_t)s * AN + a];
        p = p > q ? p : q;
    }
    unsigned g = 0xFFFFFFFFu - (unsigned)(p & 0xFFFFFFFFull);
    float best = __uint_as_float((unsigned)(p >> 32));
    out[a] = (best <= 0.0f) ? (float)NC : (float)gt_labels[g];
    ((float4*)(out + AN))[a] = ((const float4*)gt_bboxes)[g];
    out[(size_t)5 * AN + a] = best;
}

// ---------------- topk pass 1 ----------------
// Score-free hot loop: filter on iou6 > th (exact superset since sc <= 1);
// scores gathered only at flush. Bbox loads double-buffered, unit-stride.
__device__ __forceinline__ void loadB(int tb, int lane,
    const float4* __restrict__ pd4,
    float4& B0, float4& B1, float4& B2, float4& B3)
{
    int a0 = tb + lane;
    B0 = pd4[min(a0,       AN - 1)];
    B1 = pd4[min(a0 + 64,  AN - 1)];
    B2 = pd4[min(a0 + 128, AN - 1)];
    B3 = pd4[min(a0 + 192, AN - 1)];
}

__device__ __forceinline__ void procB(
    int tb, int aend, int lane, uint64_t lt,
    float4 B0, float4 B1, float4 B2, float4 B3,
    const float* __restrict__ srow,
    float4 b, float gax, float& th, int& cnt,
    float* cand_v, int* cand_i, float& inc_v, int& inc_i)
{
    int a0 = tb + lane, a1 = a0 + 64, a2 = a0 + 128, a3 = a0 + 192;
    float i60 = iou6r(b, gax, B0);
    float i61 = iou6r(b, gax, B1);
    float i62 = iou6r(b, gax, B2);
    float i63 = iou6r(b, gax, B3);
    // iou6 > th is an exact superset of m > th (sc <= 1); items with m == th
    // lose the index tie to incumbents anyway. Flush re-evaluates exactly.
    bool h0 = (i60 > th) && (a0 < aend);
    bool h1 = (i61 > th) && (a1 < aend);
    bool h2 = (i62 > th) && (a2 < aend);
    bool h3 = (i63 > th) && (a3 < aend);
    if (__any(h0 | h1 | h2 | h3)) {
        uint64_t B;
        B = __ballot(h0);
        if (h0) { int p = cnt + __popcll(B & lt); cand_v[p] = i60; cand_i[p] = a0; }
        cnt += __popcll(B);
        B = __ballot(h1);
        if (h1) { int p = cnt + __popcll(B & lt); cand_v[p] = i61; cand_i[p] = a1; }
        cnt += __popcll(B);
        B = __ballot(h2);
        if (h2) { int p = cnt + __popcll(B & lt); cand_v[p] = i62; cand_i[p] = a2; }
        cnt += __popcll(B);
        B = __ballot(h3);
        if (h3) { int p = cnt + __popcll(B & lt); cand_v[p] = i63; cand_i[p] = a3; }
        cnt += __popcll(B);
        if (cnt >= 256) {                 // cap: 255 + 256 = 511 < 512
            th = flush_x(lane, cnt, cand_v, cand_i, srow, inc_v, inc_i);
            cnt = 0;
        }
    }
}

__global__ __launch_bounds__(256, 4) void topk_pass1(
    const float* __restrict__ pd_bboxes,
    const int*   __restrict__ gt_labels,
    const float* __restrict__ gt_bboxes,
    const float* __restrict__ scT,
    float* __restrict__ out_v, int* __restrict__ out_i)
{
    __shared__ float cvA[4][512];
    __shared__ int   ciA[4][512];
    int w = threadIdx.x >> 6, lane = threadIdx.x & 63;
    float* cand_v = cvA[w]; int* cand_i = ciA[w];
    uint64_t lt = (1ull << lane) - 1ull;
    int gid = blockIdx.x * 4 + w;
    int g = gid & (GN - 1), c = gid >> 9;

    float4 b = ((const float4*)gt_bboxes)[g];
    float gax = (b.z - b.x) * (b.w - b.y);
    int lab = gt_labels[g];
    const float* srow = scT + (size_t)lab * AN;
    const float4* pd4 = (const float4*)pd_bboxes;

    int base = c * CH_LEN;
    int len = min(CH_LEN, AN - base);
    int aend = base + len;
    int NT = (len + 255) >> 8;

    float th = -FLT_MAX; int cnt = 0;
    float inc_v = -FLT_MAX; int inc_i = 0x7fffffff;   // lane r<13: rank r (metric)

    float4 X0, X1, X2, X3, Y0, Y1, Y2, Y3;
    loadB(base, lane, pd4, X0, X1, X2, X3);
    int i = 0, tb = base;
    while (true) {
        if (i + 1 < NT) loadB(tb + 256, lane, pd4, Y0, Y1, Y2, Y3);
        procB(tb, aend, lane, lt, X0, X1, X2, X3, srow,
              b, gax, th, cnt, cand_v, cand_i, inc_v, inc_i);
        ++i; tb += 256;
        if (i >= NT) break;
        if (i + 1 < NT) loadB(tb + 256, lane, pd4, X0, X1, X2, X3);
        procB(tb, aend, lane, lt, Y0, Y1, Y2, Y3, srow,
              b, gax, th, cnt, cand_v, cand_i, inc_v, inc_i);
        ++i; tb += 256;
        if (i >= NT) break;
    }

    if (cnt > 0)
        flush_x(lane, cnt, cand_v, cand_i, srow, inc_v, inc_i);

    if (lane < DUMP) {
        size_t o = ((size_t)g * CHUNKS + c) * DUMP + lane;
        out_v[o] = (lane < KK) ? inc_v : -FLT_MAX;
        out_i[o] = (lane < KK) ? inc_i : 0x7fffffff;
    }
}

// ---------------- topk pass 2: zero row + merge 8x16 dumps + scatter ----------------
__global__ __launch_bounds__(256) void topk_finalize(
    const float* __restrict__ in_v, const int* __restrict__ in_i,
    float* __restrict__ mask)
{
    int g = blockIdx.x, tid = threadIdx.x;
    float4* row4 = (float4*)(mask + (size_t)g * AN);
    float4 z = make_float4(0.f, 0.f, 0.f, 0.f);
    for (int j = tid; j < AN / 4; j += 256) row4[j] = z;
    __syncthreads();
    if (tid >= 64) return;
    int lane = tid;
    size_t rb = (size_t)g * (CHUNKS * DUMP);     // 128 entries
    float v0 = in_v[rb + lane], v1 = in_v[rb + 64 + lane];
    int   i0 = in_i[rb + lane], i1 = in_i[rb + 64 + lane];
    csw(v0, i0, v1, i1);
    #pragma unroll
    for (int r = 0; r < KK; ++r) {
        ull myp = ((ull)f2ord(v0) << 32) | (unsigned)(~i0);
        ull p = myp;
        #pragma unroll
        for (int o = 32; o >= 1; o >>= 1) {
            ull q = __shfl_xor(p, o);
            p = p > q ? p : q;
        }
        int wi = (int)~((unsigned)p);
        if (lane == r) mask[(size_t)g * AN + wi] = 1.0f;
        bool pop = (myp == p);
        v0 = pop ? v1 : v0;          i0 = pop ? i1 : i0;
        v1 = pop ? -FLT_MAX : v1;    i1 = pop ? 0x7fffffff : i1;
    }
}

// ---------------- fallbacks (small workspace) ----------------
__global__ __launch_bounds__(256) void argmax_kernel(
    const float* __restrict__ pd_scores,
    const float* __restrict__ pd_bboxes,
    const int*   __restrict__ gt_labels,
    const float* __restrict__ gt_bboxes,
    const float* __restrict__ scT, int use_t,
    float* __restrict__ out)
{
    __shared__ float4 gb[GN];
    __shared__ float  ga[GN];
    __shared__ int    gl[GN];
    int tid = threadIdx.x;
    for (int g = tid; g < GN; g += 256) {
        float4 b = reinterpret_cast<const float4*>(gt_bboxes)[g];
        gb[g] = b;
        ga[g] = (b.z - b.x) * (b.w - b.y);
        gl[g] = gt_labels[g];
    }
    __syncthreads();
    int a = blockIdx.x * 256 + tid;
    if (a >= AN) return;
    float4 pb = reinterpret_cast<const float4*>(pd_bboxes)[a];
    float best = -1.0f; int bg = 0;
    for (int g = 0; g < GN; ++g) {
        int lab = gl[g];
        float sc = use_t ? scT[(size_t)lab * AN + a] : pd_scores[(size_t)a * NC + lab];
        float m = sc * iou6r(gb[g], ga[g], pb);
        if (m > best) { best = m; bg = g; }
    }
    out[a] = (best <= 0.0f) ? (float)NC : (float)gl[bg];
    reinterpret_cast<float4*>(out + AN)[a] = gb[bg];
    out[5 * AN + a] = best;
}

__global__ __launch_bounds__(256) void topk_kernel_fallback(
    const float* __restrict__ pd_scores,
    const float* __restrict__ pd_bboxes,
    const int*   __restrict__ gt_labels,
    const float* __restrict__ gt_bboxes,
    const float* __restrict__ scT, int use_t,
    float* __restrict__ mask)
{
    __shared__ float sv[256 * KK];
    __shared__ int   si[256 * KK];
    int g = blockIdx.x, tid = threadIdx.x;
    float4 b = reinterpret_cast<const float4*>(gt_bboxes)[g];
    float gax = (b.z - b.x) * (b.w - b.y);
    int lab = gt_labels[g];
    float v[KK]; int idx[KK];
    #pragma unroll
    for (int j = 0; j < KK; ++j) { v[j] = -FLT_MAX; idx[j] = 0x7fffffff; }
    for (int a = tid; a < AN; a += 256) {
        float4 pb = reinterpret_cast<const float4*>(pd_bboxes)[a];
        float sc = use_t ? scT[(size_t)lab * AN + a] : pd_scores[(size_t)a * NC + lab];
        float m = sc * iou6r(b, gax, pb);
        insert13(v, idx, m, a);
    }
    #pragma unroll
    for (int j = 0; j < KK; ++j) { sv[tid * KK + j] = v[j]; si[tid * KK + j] = idx[j]; }
    for (int off = 128; off >= 1; off >>= 1) {
        __syncthreads();
        if (tid < off) {
            int i = 0, jj = 0;
            float ov[KK]; int oi[KK];
            #pragma unroll
            for (int t = 0; t < KK; ++t) {
                float va = sv[tid * KK + i];          int ia = si[tid * KK + i];
                float vb = sv[(tid + off) * KK + jj]; int ib = si[(tid + off) * KK + jj];
                bool ta = (va > vb) || (va == vb && ia < ib);
                ov[t] = ta ? va : vb; oi[t] = ta ? ia : ib;
                i += ta ? 1 : 0; jj += ta ? 0 : 1;
            }
            #pragma unroll
            for (int t = 0; t < KK; ++t) { sv[tid * KK + t] = ov[t]; si[tid * KK + t] = oi[t]; }
        }
    }
    __syncthreads();
    if (tid < KK) mask[(size_t)g * AN + si[tid]] = 1.0f;
}

extern "C" void kernel_launch(void* const* d_in, const int* in_sizes, int n_in,
                              void* d_out, int out_size, void* d_ws, size_t ws_size,
                              hipStream_t stream)
{
    const float* pd_scores = (const float*)d_in[0];
    const float* pd_bboxes = (const float*)d_in[1];
    const int*   gt_labels = (const int*)d_in[2];
    const float* gt_bboxes = (const float*)d_in[3];
    float* out  = (float*)d_out;
    float* mask = out + (size_t)6 * AN;

    const size_t scT_b  = (size_t)NC * AN * sizeof(float);           // 32.0 MB
    const size_t auxn   = (size_t)GN * CHUNKS * DUMP;                // 65536
    const size_t aux_b  = auxn * 8;                                  // 0.5 MB
    const size_t part_b = (size_t)GSLICE * AN * sizeof(ull);         // 6.4 MB

    float* scT   = (float*)d_ws;
    float* aux_v = (float*)((char*)d_ws + scT_b);
    int*   aux_i = (int*)(aux_v + auxn);
    ull*   part  = (ull*)((char*)d_ws + scT_b + aux_b);

    if (ws_size >= scT_b + aux_b + part_b) {
        transpose_scores<<<(AN + 63) / 64, 256, 0, stream>>>(pd_scores, scT);
        topk_pass1<<<GN * CHUNKS / 4, 256, 0, stream>>>(
            pd_bboxes, gt_labels, gt_bboxes, scT, aux_v, aux_i);
        topk_finalize<<<GN, 256, 0, stream>>>(aux_v, aux_i, mask);
        argmax_part<<<((AN + 511) / 512) * GSLICE, 256, 0, stream>>>(
            pd_bboxes, gt_labels, gt_bboxes, scT, part);
        argmax_combine<<<(AN + 255) / 256, 256, 0, stream>>>(
            part, gt_labels, gt_bboxes, out);
    } else if (ws_size >= scT_b + aux_b) {
        transpose_scores<<<(AN + 63) / 64, 256, 0, stream>>>(pd_scores, scT);
        topk_pass1<<<GN * CHUNKS / 4, 256, 0, stream>>>(
            pd_bboxes, gt_labels, gt_bboxes, scT, aux_v, aux_i);
        topk_finalize<<<GN, 256, 0, stream>>>(aux_v, aux_i, mask);
        argmax_kernel<<<(AN + 255) / 256, 256, 0, stream>>>(
            pd_scores, pd_bboxes, gt_labels, gt_bboxes, scT, 1, out);
    } else if (ws_size >= scT_b) {
        hipMemsetAsync(mask, 0, (size_t)GN * AN * sizeof(float), stream);
        transpose_scores<<<(AN + 63) / 64, 256, 0, stream>>>(pd_scores, scT);
        argmax_kernel<<<(AN + 255) / 256, 256, 0, stream>>>(
            pd_scores, pd_bboxes, gt_labels, gt_bboxes, scT, 1, out);
        topk_kernel_fallback<<<GN, 256, 0, stream>>>(
            pd_scores, pd_bboxes, gt_labels, gt_bboxes, scT, 1, mask);
    } else {
        hipMemsetAsync(mask, 0, (size_t)GN * AN * sizeof(float), stream);
        argmax_kernel<<<(AN + 255) / 256, 256, 0, stream>>>(
            pd_scores, pd_bboxes, gt_labels, gt_bboxes, scT, 0, out);
        topk_kernel_fallback<<<GN, 256, 0, stream>>>(
            pd_scores, pd_bboxes, gt_labels, gt_bboxes, scT, 0, mask);
    }
}